// Round 16
// baseline (78.776 us; speedup 1.0000x reference)
//
#include <hip/hip_runtime.h>
#include <math.h>

#define U 128
#define NIT 10   // 1-term Picard iters/layer; + 1 exact-W correction iteration

typedef __attribute__((ext_vector_type(8))) short bf16x8;
typedef __attribute__((ext_vector_type(4))) short short4v;   // LDS store type (same elem type as loads)
typedef __attribute__((ext_vector_type(4))) float f32x4;
typedef __attribute__((ext_vector_type(2))) unsigned int u32x2;
typedef __attribute__((ext_vector_type(4))) unsigned int u32x4;

__device__ inline unsigned int pack2(float a, float b) {
    // low short = bf16(a) (truncated), high short = bf16(b)
    return (__float_as_uint(a) >> 16) | (__float_as_uint(b) & 0xFFFF0000u);
}
__device__ inline float lo_of(float a) {
    return a - __uint_as_float(__float_as_uint(a) & 0xFFFF0000u);
}
__device__ inline unsigned int packrn(float a, float b) {
    // RTNE pack (v_cvt_pk_bf16_f32): low = bf16_rn(a), high = bf16_rn(b)
    unsigned int r;
    asm("v_cvt_pk_bf16_f32 %0, %1, %2" : "=v"(r) : "v"(a), "v"(b));
    return r;
}
__device__ inline float tanh_fast(float v) {
    float e = __expf(2.0f * v);
    return 1.0f - 2.0f / (e + 1.0f);
}
// R13-R15 NaN post-mortem: (a) 64-thr blocks let hipcc elide s_barrier (wave
// is "always synced"), gutting __syncthreads' fence; (b) uint-typed stores vs
// short-vector loads are TBAA-no-alias, so the scheduler may hoist next-iter
// ds_reads above this iter's ds_writes; (c) inline-asm waitcnt corrupts the
// waitcnt pass's counter model (R14). Fixes: 2-wave blocks (real barrier),
// same-elem-type LDS accesses, volatile in-loop LDS ops (HW DS pipe is
// in-order per wave, so volatile program order = correct order).
__device__ inline void lds_fence() { __syncthreads(); }
__device__ inline void lds_store4(char* p, unsigned int a, unsigned int b) {
    u32x2 v; v[0] = a; v[1] = b;
    *(volatile short4v*)p = __builtin_bit_cast(short4v, v);
}
__device__ inline bf16x8 lds_load8(const char* p) {
    bf16x8 r = *(const volatile bf16x8*)p;
    return r;
}
#define MFMA(A, B, C) __builtin_amdgcn_mfma_f32_16x16x32_bf16(A, B, C, 0, 0, 0)

// in-register f32 -> (trunc-bf16 hi, bf16 lo) split of 8 values
#define SPLIT8(P4, Q4, H, LO)                                              \
{   u32x4 h_, l_;                                                          \
    h_[0] = pack2(P4.x, P4.y); h_[1] = pack2(P4.z, P4.w);                  \
    h_[2] = pack2(Q4.x, Q4.y); h_[3] = pack2(Q4.z, Q4.w);                  \
    l_[0] = pack2(lo_of(P4.x), lo_of(P4.y));                               \
    l_[1] = pack2(lo_of(P4.z), lo_of(P4.w));                               \
    l_[2] = pack2(lo_of(Q4.x), lo_of(Q4.y));                               \
    l_[3] = pack2(lo_of(Q4.z), lo_of(Q4.w));                               \
    H  = __builtin_bit_cast(bf16x8, h_);                                   \
    LO = __builtin_bit_cast(bf16x8, l_); }

// ---------------------------------------------------------------------------
// k_gemm_in: zA = X @ Wi^T + bi (f32). R10 version (measured 8.8us, R11).
// ---------------------------------------------------------------------------
__global__ __launch_bounds__(512) void k_gemm_in(
        const float* __restrict__ X, const float* __restrict__ Wi,
        const float* __restrict__ bi, float* __restrict__ zA) {
    __shared__ f32x4 redS[4][64];
    const int tid  = threadIdx.x;
    const int w    = tid >> 6;
    const int lane = tid & 63;
    const int l15  = lane & 15;
    const int lq   = lane >> 4;
    const int slab = blockIdx.x & 127;
    const int ch   = blockIdx.x >> 7;
    const int ct   = w & 3;
    const int kh   = w >> 2;
    const int r0   = slab * 16;
    const int cb   = ch * 64 + ct * 16;
    const int colA = cb + l15;
    const int KD   = 784;

    const float* xp = &X[(long)(r0 + l15) * KD];
    const float* wp = &Wi[(long)colA * KD];

    f32x4 a0 = {0.f, 0.f, 0.f, 0.f};
    f32x4 a1 = {0.f, 0.f, 0.f, 0.f};
    f32x4 a2 = {0.f, 0.f, 0.f, 0.f};
    if (kh == 0) {
        float4 b4 = *(const float4*)&bi[cb + lq * 4];
        a0[0] = b4.x; a0[1] = b4.y; a0[2] = b4.z; a0[3] = b4.w;
    }

    const int kbase = kh ? 384 : 0;
    #pragma unroll 6
    for (int c = 0; c < 12; ++c) {
        const int k = kbase + c * 32 + lq * 8;
        float4 xa = *(const float4*)&xp[k];
        float4 xb = *(const float4*)&xp[k + 4];
        float4 wa = *(const float4*)&wp[k];
        float4 wb = *(const float4*)&wp[k + 4];
        bf16x8 ah, al, bh, bl;
        SPLIT8(xa, xb, ah, al)
        SPLIT8(wa, wb, bh, bl)
        a0 = MFMA(bh, ah, a0);     // Wh . xh
        a1 = MFMA(bh, al, a1);     // Wh . xl
        a2 = MFMA(bl, ah, a2);     // Wl . xh
    }
    if (kh) {   // tail k = 768..783 (valid lq<2)
        float4 z4 = make_float4(0.f, 0.f, 0.f, 0.f);
        float4 xa = z4, xb = z4, wa = z4, wb = z4;
        if (lq < 2) {
            const int k = 768 + lq * 8;
            xa = *(const float4*)&xp[k];
            xb = *(const float4*)&xp[k + 4];
            wa = *(const float4*)&wp[k];
            wb = *(const float4*)&wp[k + 4];
        }
        bf16x8 ah, al, bh, bl;
        SPLIT8(xa, xb, ah, al)
        SPLIT8(wa, wb, bh, bl)
        a0 = MFMA(bh, ah, a0);
        a1 = MFMA(bh, al, a1);
        a2 = MFMA(bl, ah, a2);
    }

    f32x4 r;
    #pragma unroll
    for (int i = 0; i < 4; ++i) r[i] = a0[i] + a1[i] + a2[i];

    if (kh) redS[ct][lane] = r;
    __syncthreads();
    if (!kh) {
        f32x4 o = redS[ct][lane];
        float4 st;
        st.x = r[0] + o[0]; st.y = r[1] + o[1];
        st.z = r[2] + o[2]; st.w = r[3] + o[3];
        *(float4*)&zA[(long)(r0 + l15) * U + cb + lq * 4] = st;
    }
}

// ---------------------------------------------------------------------------
// k_picard v3d: wave-private recurrence, 2 waves/block (REAL barriers).
// grid = B/32 blocks x 128 threads. Wave w owns rows blockIdx*32 + 16w ..
// +15, all 128 cols; z stays in that wave's private LDS buffers. Waves share
// nothing; barriers only enforce ordering. Volatile, short-typed LDS ops.
// In-loop W = 1-term RTNE bf16 (whf[8][4] = 128 VGPR, launch_bounds(128,1));
// after NIT iters one exact-W iteration (JIT W-lo) repairs the W-quant shift;
// final z* stays f32 -> 3-term output GEMM + per-wave softmax.
// LDS z: byte(r,c) = r*256 + ((2c) ^ ((r&7)<<4)); per wave: buf0 hi, buf1 lo.
// ---------------------------------------------------------------------------
__global__ __launch_bounds__(128, 1) void k_picard(
        const float* __restrict__ zA, const float* __restrict__ Wb,
        const float* __restrict__ Wo, const float* __restrict__ bo,
        float* __restrict__ Out, int L) {
    __shared__ unsigned short zS[2][2][16 * U];   // [wave][hi/lo] = 16 KB

    const int w    = threadIdx.x >> 6;
    const int lane = threadIdx.x & 63;
    const int l15  = lane & 15;
    const int lq   = lane >> 4;
    const int r0   = blockIdx.x * 32 + w * 16;

    const int swz = (l15 & 7) << 4;
    int offA[4], offW[8];
    #pragma unroll
    for (int ks = 0; ks < 4; ++ks)
        offA[ks] = l15 * 256 + ((64 * ks + 16 * lq) ^ swz);
    #pragma unroll
    for (int t = 0; t < 8; ++t)
        offW[t] = l15 * 256 + ((32 * t + 8 * lq) ^ swz);

    char* zhB = (char*)&zS[w][0][0];
    char* zlB = (char*)&zS[w][1][0];

    // x for layer 0: lane l15 = batch row; xf[t][i] = col 16t+4lq+i (D layout)
    f32x4 xf[8];
    #pragma unroll
    for (int t = 0; t < 8; ++t) {
        float4 v = *(const float4*)&zA[(long)(r0 + l15) * U + 16 * t + 4 * lq];
        xf[t][0] = v.x; xf[t][1] = v.y; xf[t][2] = v.z; xf[t][3] = v.w;
    }

    for (int l = 0; l < L; ++l) {
        const float* wl0 = &Wb[(long)l * U * U];

        // Wh (RTNE 1-term) -> registers for the whole layer.
        bf16x8 whf[8][4];
        #pragma unroll
        for (int t = 0; t < 8; ++t) {
            const float* wrow = &wl0[(16 * t + l15) * U];
            #pragma unroll
            for (int ks = 0; ks < 4; ++ks) {
                const float* wp = &wrow[32 * ks + 8 * lq];
                float4 p = *(const float4*)&wp[0];
                float4 q = *(const float4*)&wp[4];
                u32x4 h;
                h[0] = packrn(p.x, p.y); h[1] = packrn(p.z, p.w);
                h[2] = packrn(q.x, q.y); h[3] = packrn(q.z, q.w);
                whf[t][ks] = __builtin_bit_cast(bf16x8, h);
            }
        }

        // z0 = tanh(x) -> LDS buf0
        #pragma unroll
        for (int t = 0; t < 8; ++t) {
            float z0 = tanh_fast(xf[t][0]), z1 = tanh_fast(xf[t][1]);
            float z2 = tanh_fast(xf[t][2]), z3 = tanh_fast(xf[t][3]);
            lds_store4(zhB + offW[t], packrn(z0, z1), packrn(z2, z3));
        }

        // NIT fence-ordered iterations (1-term W)
        for (int it = 0; it < NIT; ++it) {
            lds_fence();                       // prior writes -> these reads
            bf16x8 zB[4];
            #pragma unroll
            for (int ks = 0; ks < 4; ++ks)
                zB[ks] = lds_load8(zhB + offA[ks]);
            #pragma unroll
            for (int t = 0; t < 8; ++t) {
                f32x4 d = xf[t];
                d = MFMA(whf[t][0], zB[0], d);
                d = MFMA(whf[t][1], zB[1], d);
                d = MFMA(whf[t][2], zB[2], d);
                d = MFMA(whf[t][3], zB[3], d);
                float z0 = tanh_fast(d[0]), z1 = tanh_fast(d[1]);
                float z2 = tanh_fast(d[2]), z3 = tanh_fast(d[3]);
                lds_store4(zhB + offW[t], packrn(z0, z1), packrn(z2, z3));
            }
        }

        // One exact-W correction iteration (JIT W-lo). Result -> xf (f32).
        {
            lds_fence();
            bf16x8 zB[4];
            #pragma unroll
            for (int ks = 0; ks < 4; ++ks)
                zB[ks] = lds_load8(zhB + offA[ks]);
            #pragma unroll
            for (int t = 0; t < 8; ++t) {
                const float* wrow = &wl0[(16 * t + l15) * U];
                f32x4 d = xf[t];
                #pragma unroll
                for (int ks = 0; ks < 4; ++ks) {
                    const float* wp = &wrow[32 * ks + 8 * lq];
                    float4 p = *(const float4*)&wp[0];
                    float4 q = *(const float4*)&wp[4];
                    u32x4 h = __builtin_bit_cast(u32x4, whf[t][ks]);
                    float lo0 = p.x - __uint_as_float(h[0] << 16);
                    float lo1 = p.y - __uint_as_float(h[0] & 0xFFFF0000u);
                    float lo2 = p.z - __uint_as_float(h[1] << 16);
                    float lo3 = p.w - __uint_as_float(h[1] & 0xFFFF0000u);
                    float lo4 = q.x - __uint_as_float(h[2] << 16);
                    float lo5 = q.y - __uint_as_float(h[2] & 0xFFFF0000u);
                    float lo6 = q.z - __uint_as_float(h[3] << 16);
                    float lo7 = q.w - __uint_as_float(h[3] & 0xFFFF0000u);
                    u32x4 lw;
                    lw[0] = packrn(lo0, lo1); lw[1] = packrn(lo2, lo3);
                    lw[2] = packrn(lo4, lo5); lw[3] = packrn(lo6, lo7);
                    bf16x8 wlf = __builtin_bit_cast(bf16x8, lw);
                    d = MFMA(whf[t][ks], zB[ks], d);
                    d = MFMA(wlf, zB[ks], d);
                }
                xf[t][0] = tanh_fast(d[0]);
                xf[t][1] = tanh_fast(d[1]);
                xf[t][2] = tanh_fast(d[2]);
                xf[t][3] = tanh_fast(d[3]);
            }
        }
        lds_fence();   // correction reads done before next layer's z0 writes
    }

    // ---------------- Phase 3: out = softmax(z @ Wo^T + bo) ----------------
    // Final z* (f32, in xf) -> LDS hi (buf0) + lo (buf1) for 3-term B-frags.
    #pragma unroll
    for (int t = 0; t < 8; ++t) {
        unsigned int h0 = packrn(xf[t][0], xf[t][1]);
        unsigned int h1 = packrn(xf[t][2], xf[t][3]);
        float lo0 = xf[t][0] - __uint_as_float(h0 << 16);
        float lo1 = xf[t][1] - __uint_as_float(h0 & 0xFFFF0000u);
        float lo2 = xf[t][2] - __uint_as_float(h1 << 16);
        float lo3 = xf[t][3] - __uint_as_float(h1 & 0xFFFF0000u);
        lds_store4(zhB + offW[t], h0, h1);
        lds_store4(zlB + offW[t], packrn(lo0, lo1), packrn(lo2, lo3));
    }
    lds_fence();

    // A-frag: Wo rows (classes, pad >=10 with zeros), 2-term split
    bf16x8 woh[4], wol[4];
    #pragma unroll
    for (int ks = 0; ks < 4; ++ks) {
        float4 p = make_float4(0.f, 0.f, 0.f, 0.f), q = p;
        if (l15 < 10) {
            const float* worow = &Wo[l15 * U + ks * 32 + lq * 8];
            p = *(const float4*)&worow[0];
            q = *(const float4*)&worow[4];
        }
        SPLIT8(p, q, woh[ks], wol[ks])
    }
    bf16x8 zf[4], zl[4];
    #pragma unroll
    for (int ks = 0; ks < 4; ++ks) {
        zf[ks] = lds_load8(zhB + offA[ks]);
        zl[ks] = lds_load8(zlB + offA[ks]);
    }

    f32x4 d0 = {0.f, 0.f, 0.f, 0.f};
    f32x4 d1 = d0, d2 = d0;
    #pragma unroll
    for (int ks = 0; ks < 4; ++ks) {
        d0 = MFMA(woh[ks], zf[ks], d0);
        d1 = MFMA(wol[ks], zf[ks], d1);
        d2 = MFMA(woh[ks], zl[ks], d2);
    }
    // lane l15 = batch row, reg i -> class 4lq+i
    float lg[4];
    #pragma unroll
    for (int i = 0; i < 4; ++i) {
        const int c = 4 * lq + i;
        lg[i] = (c < 10) ? (d0[i] + d1[i] + d2[i] + bo[c]) : -1e30f;
    }
    float m = fmaxf(fmaxf(lg[0], lg[1]), fmaxf(lg[2], lg[3]));
    m = fmaxf(m, __shfl_xor(m, 16));
    m = fmaxf(m, __shfl_xor(m, 32));
    float e[4], s = 0.f;
    #pragma unroll
    for (int i = 0; i < 4; ++i) { e[i] = __expf(lg[i] - m); s += e[i]; }
    s += __shfl_xor(s, 16);
    s += __shfl_xor(s, 32);
    const float inv = 1.0f / s;
    #pragma unroll
    for (int i = 0; i < 4; ++i) {
        const int c = 4 * lq + i;
        if (c < 10) Out[(long)(r0 + l15) * 10 + c] = e[i] * inv;
    }
}

// ---------------------------------------------------------------------------
extern "C" void kernel_launch(void* const* d_in, const int* in_sizes, int n_in,
                              void* d_out, int out_size, void* d_ws, size_t ws_size,
                              hipStream_t stream) {
    const float* x  = (const float*)d_in[0];   // [B,784]
    const float* Wi = (const float*)d_in[1];   // [128,784]
    const float* bi = (const float*)d_in[2];   // [128]
    const float* Wb = (const float*)d_in[3];   // [L,128,128]
    const float* Wo = (const float*)d_in[4];   // [10,128]
    const float* bo = (const float*)d_in[5];   // [10]
    float* out = (float*)d_out;

    const int DIN = 784;
    const int B   = in_sizes[0] / DIN;             // 2048
    const int L   = in_sizes[3] / (U * U);         // 2

    float* zA = (float*)d_ws;                      // [B,U] f32

    k_gemm_in<<<256, 512, 0, stream>>>(x, Wi, bi, zA);
    k_picard<<<B / 32, 128, 0, stream>>>(zA, Wb, Wo, bo, out, L);
}

// Round 17
// 62.872 us; speedup vs baseline: 1.2530x; 1.2530x over previous
//
#include <hip/hip_runtime.h>
#include <math.h>

#define U 128
#define NIT 10   // 1-term Picard iters/layer + 1 exact-W correction (numerics
                 // validated in R16: absmax 1.95e-3)

typedef __attribute__((ext_vector_type(8))) short bf16x8;
typedef __attribute__((ext_vector_type(4))) float f32x4;
typedef __attribute__((ext_vector_type(2))) unsigned int u32x2;
typedef __attribute__((ext_vector_type(4))) unsigned int u32x4;

__device__ inline unsigned int pack2(float a, float b) {
    // low short = bf16(a) (truncated), high short = bf16(b)
    return (__float_as_uint(a) >> 16) | (__float_as_uint(b) & 0xFFFF0000u);
}
__device__ inline float lo_of(float a) {
    return a - __uint_as_float(__float_as_uint(a) & 0xFFFF0000u);
}
__device__ inline unsigned int packrn(float a, float b) {
    // RTNE pack (v_cvt_pk_bf16_f32): low = bf16_rn(a), high = bf16_rn(b)
    unsigned int r;
    asm("v_cvt_pk_bf16_f32 %0, %1, %2" : "=v"(r) : "v"(a), "v"(b));
    return r;
}
__device__ inline float tanh_fast(float v) {
    float e = __expf(2.0f * v);
    return 1.0f - 2.0f / (e + 1.0f);
}
#define MFMA(A, B, C) __builtin_amdgcn_mfma_f32_16x16x32_bf16(A, B, C, 0, 0, 0)

// in-register f32 -> (trunc-bf16 hi, bf16 lo) split of 8 values
#define SPLIT8(P4, Q4, H, LO)                                              \
{   u32x4 h_, l_;                                                          \
    h_[0] = pack2(P4.x, P4.y); h_[1] = pack2(P4.z, P4.w);                  \
    h_[2] = pack2(Q4.x, Q4.y); h_[3] = pack2(Q4.z, Q4.w);                  \
    l_[0] = pack2(lo_of(P4.x), lo_of(P4.y));                               \
    l_[1] = pack2(lo_of(P4.z), lo_of(P4.w));                               \
    l_[2] = pack2(lo_of(Q4.x), lo_of(Q4.y));                               \
    l_[3] = pack2(lo_of(Q4.z), lo_of(Q4.w));                               \
    H  = __builtin_bit_cast(bf16x8, h_);                                   \
    LO = __builtin_bit_cast(bf16x8, l_); }

// ---------------------------------------------------------------------------
// k_gemm_in: zA = X @ Wi^T + bi (f32). R10 version (measured 8.8us, R11).
// ---------------------------------------------------------------------------
__global__ __launch_bounds__(512) void k_gemm_in(
        const float* __restrict__ X, const float* __restrict__ Wi,
        const float* __restrict__ bi, float* __restrict__ zA) {
    __shared__ f32x4 redS[4][64];
    const int tid  = threadIdx.x;
    const int w    = tid >> 6;
    const int lane = tid & 63;
    const int l15  = lane & 15;
    const int lq   = lane >> 4;
    const int slab = blockIdx.x & 127;
    const int ch   = blockIdx.x >> 7;
    const int ct   = w & 3;
    const int kh   = w >> 2;
    const int r0   = slab * 16;
    const int cb   = ch * 64 + ct * 16;
    const int colA = cb + l15;
    const int KD   = 784;

    const float* xp = &X[(long)(r0 + l15) * KD];
    const float* wp = &Wi[(long)colA * KD];

    f32x4 a0 = {0.f, 0.f, 0.f, 0.f};
    f32x4 a1 = {0.f, 0.f, 0.f, 0.f};
    f32x4 a2 = {0.f, 0.f, 0.f, 0.f};
    if (kh == 0) {
        float4 b4 = *(const float4*)&bi[cb + lq * 4];
        a0[0] = b4.x; a0[1] = b4.y; a0[2] = b4.z; a0[3] = b4.w;
    }

    const int kbase = kh ? 384 : 0;
    #pragma unroll 6
    for (int c = 0; c < 12; ++c) {
        const int k = kbase + c * 32 + lq * 8;
        float4 xa = *(const float4*)&xp[k];
        float4 xb = *(const float4*)&xp[k + 4];
        float4 wa = *(const float4*)&wp[k];
        float4 wb = *(const float4*)&wp[k + 4];
        bf16x8 ah, al, bh, bl;
        SPLIT8(xa, xb, ah, al)
        SPLIT8(wa, wb, bh, bl)
        a0 = MFMA(bh, ah, a0);     // Wh . xh
        a1 = MFMA(bh, al, a1);     // Wh . xl
        a2 = MFMA(bl, ah, a2);     // Wl . xh
    }
    if (kh) {   // tail k = 768..783 (valid lq<2)
        float4 z4 = make_float4(0.f, 0.f, 0.f, 0.f);
        float4 xa = z4, xb = z4, wa = z4, wb = z4;
        if (lq < 2) {
            const int k = 768 + lq * 8;
            xa = *(const float4*)&xp[k];
            xb = *(const float4*)&xp[k + 4];
            wa = *(const float4*)&wp[k];
            wb = *(const float4*)&wp[k + 4];
        }
        bf16x8 ah, al, bh, bl;
        SPLIT8(xa, xb, ah, al)
        SPLIT8(wa, wb, bh, bl)
        a0 = MFMA(bh, ah, a0);
        a1 = MFMA(bh, al, a1);
        a2 = MFMA(bl, ah, a2);
    }

    f32x4 r;
    #pragma unroll
    for (int i = 0; i < 4; ++i) r[i] = a0[i] + a1[i] + a2[i];

    if (kh) redS[ct][lane] = r;
    __syncthreads();
    if (!kh) {
        f32x4 o = redS[ct][lane];
        float4 st;
        st.x = r[0] + o[0]; st.y = r[1] + o[1];
        st.z = r[2] + o[2]; st.w = r[3] + o[3];
        *(float4*)&zA[(long)(r0 + l15) * U + cb + lq * 4] = st;
    }
}

// ---------------------------------------------------------------------------
// k_picard v4: REGISTER-ONLY recurrence -- no LDS, no barriers, no shuffles.
// Key: with tile->column map M(t,m) = 32*(t>>1) + 8*(m>>2) + 4*(t&1) + (m&3),
// the swapped-MFMA D output (lane l15 = batch row; tile t regs = cols
// colB[t]..+3) IS the next iteration's B-operand, lane-locally:
//   B-frag[ks] = { zr[2ks][0..3], zr[2ks+1][0..3] }   (e<4 -> tile 2ks,
//   e>=4 -> tile 2ks+1; both at this lane's own lq).
// Cost: A-frags load W rows M(t,l15) instead of 16t+l15 (free), x loads use
// colB[t] offsets (4-aligned float4s, free). The R13-R16 LDS-ordering hazard
// class is eliminated structurally.
// Numerics = R16 exactly (1-term RTNE W + RTNE-bf16 z in-loop, NIT=10, one
// exact-W JIT-lo correction per layer, f32 z* + 3-term output GEMM).
// grid = B/16 blocks x 64 threads (one wave, 16 rows x 128 cols).
// ---------------------------------------------------------------------------
__global__ __launch_bounds__(64, 1) void k_picard(
        const float* __restrict__ zA, const float* __restrict__ Wb,
        const float* __restrict__ Wo, const float* __restrict__ bo,
        float* __restrict__ Out, int L) {
    const int lane = threadIdx.x & 63;
    const int l15  = lane & 15;
    const int lq   = lane >> 4;
    const int r0   = blockIdx.x * 16;

    int rowM[8], colB[8];
    #pragma unroll
    for (int t = 0; t < 8; ++t) {
        rowM[t] = 32 * (t >> 1) + 8 * (l15 >> 2) + 4 * (t & 1) + (l15 & 3);
        colB[t] = 32 * (t >> 1) + 8 * lq + 4 * (t & 1);
    }

    // x for layer 0 (D-layout under M): xf[t][i] = zlin[r0+l15][colB[t]+i]
    f32x4 xf[8];
    #pragma unroll
    for (int t = 0; t < 8; ++t) {
        float4 v = *(const float4*)&zA[(long)(r0 + l15) * U + colB[t]];
        xf[t][0] = v.x; xf[t][1] = v.y; xf[t][2] = v.z; xf[t][3] = v.w;
    }

    u32x2 zpk[8];   // current z, RTNE-bf16 packed pairs (the B-operand data)

    // build the 4 B-frags from zpk (pure register moves)
    #define BUILD_B(B)                                                     \
    {   _Pragma("unroll")                                                  \
        for (int ks = 0; ks < 4; ++ks) {                                   \
            u32x4 b_;                                                      \
            b_[0] = zpk[2 * ks][0];     b_[1] = zpk[2 * ks][1];            \
            b_[2] = zpk[2 * ks + 1][0]; b_[3] = zpk[2 * ks + 1][1];        \
            B[ks] = __builtin_bit_cast(bf16x8, b_);                        \
        } }

    for (int l = 0; l < L; ++l) {
        const float* wl0 = &Wb[(long)l * U * U];

        // Wh (RTNE 1-term) -> registers for the whole layer (A-frag rows M)
        bf16x8 whf[8][4];
        #pragma unroll
        for (int t = 0; t < 8; ++t) {
            const float* wrow = &wl0[rowM[t] * U];
            #pragma unroll
            for (int ks = 0; ks < 4; ++ks) {
                const float* wp = &wrow[32 * ks + 8 * lq];
                float4 p = *(const float4*)&wp[0];
                float4 q = *(const float4*)&wp[4];
                u32x4 h;
                h[0] = packrn(p.x, p.y); h[1] = packrn(p.z, p.w);
                h[2] = packrn(q.x, q.y); h[3] = packrn(q.z, q.w);
                whf[t][ks] = __builtin_bit_cast(bf16x8, h);
            }
        }

        // z0 = tanh(x)
        #pragma unroll
        for (int t = 0; t < 8; ++t) {
            float z0 = tanh_fast(xf[t][0]), z1 = tanh_fast(xf[t][1]);
            float z2 = tanh_fast(xf[t][2]), z3 = tanh_fast(xf[t][3]);
            zpk[t][0] = packrn(z0, z1);
            zpk[t][1] = packrn(z2, z3);
        }

        // NIT register-only iterations (1-term W)
        for (int it = 0; it < NIT; ++it) {
            bf16x8 B[4];
            BUILD_B(B)                 // copies: safe to overwrite zpk below
            #pragma unroll
            for (int t = 0; t < 8; ++t) {
                f32x4 d = xf[t];
                d = MFMA(whf[t][0], B[0], d);
                d = MFMA(whf[t][1], B[1], d);
                d = MFMA(whf[t][2], B[2], d);
                d = MFMA(whf[t][3], B[3], d);
                float z0 = tanh_fast(d[0]), z1 = tanh_fast(d[1]);
                float z2 = tanh_fast(d[2]), z3 = tanh_fast(d[3]);
                zpk[t][0] = packrn(z0, z1);
                zpk[t][1] = packrn(z2, z3);
            }
        }

        // One exact-W correction iteration (JIT W-lo). Result -> xf (f32).
        {
            bf16x8 B[4];
            BUILD_B(B)
            #pragma unroll
            for (int t = 0; t < 8; ++t) {
                const float* wrow = &wl0[rowM[t] * U];
                f32x4 d = xf[t];
                #pragma unroll
                for (int ks = 0; ks < 4; ++ks) {
                    const float* wp = &wrow[32 * ks + 8 * lq];
                    float4 p = *(const float4*)&wp[0];
                    float4 q = *(const float4*)&wp[4];
                    u32x4 h = __builtin_bit_cast(u32x4, whf[t][ks]);
                    float lo0 = p.x - __uint_as_float(h[0] << 16);
                    float lo1 = p.y - __uint_as_float(h[0] & 0xFFFF0000u);
                    float lo2 = p.z - __uint_as_float(h[1] << 16);
                    float lo3 = p.w - __uint_as_float(h[1] & 0xFFFF0000u);
                    float lo4 = q.x - __uint_as_float(h[2] << 16);
                    float lo5 = q.y - __uint_as_float(h[2] & 0xFFFF0000u);
                    float lo6 = q.z - __uint_as_float(h[3] << 16);
                    float lo7 = q.w - __uint_as_float(h[3] & 0xFFFF0000u);
                    u32x4 lw;
                    lw[0] = packrn(lo0, lo1); lw[1] = packrn(lo2, lo3);
                    lw[2] = packrn(lo4, lo5); lw[3] = packrn(lo6, lo7);
                    bf16x8 wlf = __builtin_bit_cast(bf16x8, lw);
                    d = MFMA(whf[t][ks], B[ks], d);
                    d = MFMA(wlf, B[ks], d);
                }
                xf[t][0] = tanh_fast(d[0]);
                xf[t][1] = tanh_fast(d[1]);
                xf[t][2] = tanh_fast(d[2]);
                xf[t][3] = tanh_fast(d[3]);
            }
        }
    }

    // ---------------- Phase 3: out = softmax(z @ Wo^T + bo) ----------------
    // 3-term z (hi + lo), all in-register via the same lane-local B build.
    u32x2 zlo[8];
    #pragma unroll
    for (int t = 0; t < 8; ++t) {
        unsigned int h0 = packrn(xf[t][0], xf[t][1]);
        unsigned int h1 = packrn(xf[t][2], xf[t][3]);
        zpk[t][0] = h0; zpk[t][1] = h1;
        float lo0 = xf[t][0] - __uint_as_float(h0 << 16);
        float lo1 = xf[t][1] - __uint_as_float(h0 & 0xFFFF0000u);
        float lo2 = xf[t][2] - __uint_as_float(h1 << 16);
        float lo3 = xf[t][3] - __uint_as_float(h1 & 0xFFFF0000u);
        zlo[t][0] = packrn(lo0, lo1);
        zlo[t][1] = packrn(lo2, lo3);
    }
    bf16x8 Bh[4], Bl[4];
    BUILD_B(Bh)
    {   // build Bl from zlo
        #pragma unroll
        for (int ks = 0; ks < 4; ++ks) {
            u32x4 b_;
            b_[0] = zlo[2 * ks][0];     b_[1] = zlo[2 * ks][1];
            b_[2] = zlo[2 * ks + 1][0]; b_[3] = zlo[2 * ks + 1][1];
            Bl[ks] = __builtin_bit_cast(bf16x8, b_);
        }
    }

    // A-frag: Wo rows (classes, pad >=10 with zeros), 2-term split.
    // Wo k-cols are physical (k-slot -> col map is identity).
    bf16x8 woh[4], wol[4];
    #pragma unroll
    for (int ks = 0; ks < 4; ++ks) {
        float4 p = make_float4(0.f, 0.f, 0.f, 0.f), q = p;
        if (l15 < 10) {
            const float* worow = &Wo[l15 * U + ks * 32 + lq * 8];
            p = *(const float4*)&worow[0];
            q = *(const float4*)&worow[4];
        }
        SPLIT8(p, q, woh[ks], wol[ks])
    }

    f32x4 d0 = {0.f, 0.f, 0.f, 0.f};
    f32x4 d1 = d0, d2 = d0;
    #pragma unroll
    for (int ks = 0; ks < 4; ++ks) {
        d0 = MFMA(woh[ks], Bh[ks], d0);
        d1 = MFMA(wol[ks], Bh[ks], d1);
        d2 = MFMA(woh[ks], Bl[ks], d2);
    }
    // lane l15 = batch row, reg i -> class 4lq+i
    float lg[4];
    #pragma unroll
    for (int i = 0; i < 4; ++i) {
        const int c = 4 * lq + i;
        lg[i] = (c < 10) ? (d0[i] + d1[i] + d2[i] + bo[c]) : -1e30f;
    }
    float m = fmaxf(fmaxf(lg[0], lg[1]), fmaxf(lg[2], lg[3]));
    m = fmaxf(m, __shfl_xor(m, 16));
    m = fmaxf(m, __shfl_xor(m, 32));
    float e[4], s = 0.f;
    #pragma unroll
    for (int i = 0; i < 4; ++i) { e[i] = __expf(lg[i] - m); s += e[i]; }
    s += __shfl_xor(s, 16);
    s += __shfl_xor(s, 32);
    const float inv = 1.0f / s;
    #pragma unroll
    for (int i = 0; i < 4; ++i) {
        const int c = 4 * lq + i;
        if (c < 10) Out[(long)(r0 + l15) * 10 + c] = e[i] * inv;
    }
}

// ---------------------------------------------------------------------------
extern "C" void kernel_launch(void* const* d_in, const int* in_sizes, int n_in,
                              void* d_out, int out_size, void* d_ws, size_t ws_size,
                              hipStream_t stream) {
    const float* x  = (const float*)d_in[0];   // [B,784]
    const float* Wi = (const float*)d_in[1];   // [128,784]
    const float* bi = (const float*)d_in[2];   // [128]
    const float* Wb = (const float*)d_in[3];   // [L,128,128]
    const float* Wo = (const float*)d_in[4];   // [10,128]
    const float* bo = (const float*)d_in[5];   // [10]
    float* out = (float*)d_out;

    const int DIN = 784;
    const int B   = in_sizes[0] / DIN;             // 2048
    const int L   = in_sizes[3] / (U * U);         // 2

    float* zA = (float*)d_ws;                      // [B,U] f32

    k_gemm_in<<<256, 512, 0, stream>>>(x, Wi, bi, zA);
    k_picard<<<B / 16, 64, 0, stream>>>(zA, Wb, Wo, bo, out, L);
}

// Round 18
// 47.722 us; speedup vs baseline: 1.6507x; 1.3175x over previous
//
#include <hip/hip_runtime.h>
#include <math.h>

#define U 128
#define NIT 10   // 1-term Picard iters/layer + 1 exact-W correction (numerics
                 // validated in R16/R17: absmax 1.95e-3)

typedef __attribute__((ext_vector_type(8))) short bf16x8;
typedef __attribute__((ext_vector_type(4))) float f32x4;
typedef __attribute__((ext_vector_type(2))) unsigned int u32x2;
typedef __attribute__((ext_vector_type(4))) unsigned int u32x4;

__device__ inline unsigned int pack2(float a, float b) {
    // low short = bf16(a) (truncated), high short = bf16(b)
    return (__float_as_uint(a) >> 16) | (__float_as_uint(b) & 0xFFFF0000u);
}
__device__ inline float lo_of(float a) {
    return a - __uint_as_float(__float_as_uint(a) & 0xFFFF0000u);
}
__device__ inline unsigned int packrn(float a, float b) {
    // RTNE pack (v_cvt_pk_bf16_f32): low = bf16_rn(a), high = bf16_rn(b)
    unsigned int r;
    asm("v_cvt_pk_bf16_f32 %0, %1, %2" : "=v"(r) : "v"(a), "v"(b));
    return r;
}
// R17 post-mortem: f32 division expands to v_div_scale/v_div_fmas/v_div_fixup
// which serialize through VCC -- 32 divs/iter ~= 5400 cy, 88% of the loop.
// v_rcp_f32 is a plain pipelined transcendental (no VCC), ~1 ULP: irrelevant
// vs the 2e-3 bf16-z budget. tanh = 1 - 2*rcp(exp(2v)+1).
__device__ inline float rcp_fast(float x) {
    float r;
    asm("v_rcp_f32 %0, %1" : "=v"(r) : "v"(x));
    return r;
}
__device__ inline float tanh_fast(float v) {
    float e = __expf(2.0f * v);
    return __builtin_fmaf(-2.0f, rcp_fast(e + 1.0f), 1.0f);
}
#define MFMA(A, B, C) __builtin_amdgcn_mfma_f32_16x16x32_bf16(A, B, C, 0, 0, 0)

// in-register f32 -> (trunc-bf16 hi, bf16 lo) split of 8 values
#define SPLIT8(P4, Q4, H, LO)                                              \
{   u32x4 h_, l_;                                                          \
    h_[0] = pack2(P4.x, P4.y); h_[1] = pack2(P4.z, P4.w);                  \
    h_[2] = pack2(Q4.x, Q4.y); h_[3] = pack2(Q4.z, Q4.w);                  \
    l_[0] = pack2(lo_of(P4.x), lo_of(P4.y));                               \
    l_[1] = pack2(lo_of(P4.z), lo_of(P4.w));                               \
    l_[2] = pack2(lo_of(Q4.x), lo_of(Q4.y));                               \
    l_[3] = pack2(lo_of(Q4.z), lo_of(Q4.w));                               \
    H  = __builtin_bit_cast(bf16x8, h_);                                   \
    LO = __builtin_bit_cast(bf16x8, l_); }

// ---------------------------------------------------------------------------
// k_gemm_in: zA = X @ Wi^T + bi (f32). R10 version (measured 8.8us, R11).
// ---------------------------------------------------------------------------
__global__ __launch_bounds__(512) void k_gemm_in(
        const float* __restrict__ X, const float* __restrict__ Wi,
        const float* __restrict__ bi, float* __restrict__ zA) {
    __shared__ f32x4 redS[4][64];
    const int tid  = threadIdx.x;
    const int w    = tid >> 6;
    const int lane = tid & 63;
    const int l15  = lane & 15;
    const int lq   = lane >> 4;
    const int slab = blockIdx.x & 127;
    const int ch   = blockIdx.x >> 7;
    const int ct   = w & 3;
    const int kh   = w >> 2;
    const int r0   = slab * 16;
    const int cb   = ch * 64 + ct * 16;
    const int colA = cb + l15;
    const int KD   = 784;

    const float* xp = &X[(long)(r0 + l15) * KD];
    const float* wp = &Wi[(long)colA * KD];

    f32x4 a0 = {0.f, 0.f, 0.f, 0.f};
    f32x4 a1 = {0.f, 0.f, 0.f, 0.f};
    f32x4 a2 = {0.f, 0.f, 0.f, 0.f};
    if (kh == 0) {
        float4 b4 = *(const float4*)&bi[cb + lq * 4];
        a0[0] = b4.x; a0[1] = b4.y; a0[2] = b4.z; a0[3] = b4.w;
    }

    const int kbase = kh ? 384 : 0;
    #pragma unroll 6
    for (int c = 0; c < 12; ++c) {
        const int k = kbase + c * 32 + lq * 8;
        float4 xa = *(const float4*)&xp[k];
        float4 xb = *(const float4*)&xp[k + 4];
        float4 wa = *(const float4*)&wp[k];
        float4 wb = *(const float4*)&wp[k + 4];
        bf16x8 ah, al, bh, bl;
        SPLIT8(xa, xb, ah, al)
        SPLIT8(wa, wb, bh, bl)
        a0 = MFMA(bh, ah, a0);     // Wh . xh
        a1 = MFMA(bh, al, a1);     // Wh . xl
        a2 = MFMA(bl, ah, a2);     // Wl . xh
    }
    if (kh) {   // tail k = 768..783 (valid lq<2)
        float4 z4 = make_float4(0.f, 0.f, 0.f, 0.f);
        float4 xa = z4, xb = z4, wa = z4, wb = z4;
        if (lq < 2) {
            const int k = 768 + lq * 8;
            xa = *(const float4*)&xp[k];
            xb = *(const float4*)&xp[k + 4];
            wa = *(const float4*)&wp[k];
            wb = *(const float4*)&wp[k + 4];
        }
        bf16x8 ah, al, bh, bl;
        SPLIT8(xa, xb, ah, al)
        SPLIT8(wa, wb, bh, bl)
        a0 = MFMA(bh, ah, a0);
        a1 = MFMA(bh, al, a1);
        a2 = MFMA(bl, ah, a2);
    }

    f32x4 r;
    #pragma unroll
    for (int i = 0; i < 4; ++i) r[i] = a0[i] + a1[i] + a2[i];

    if (kh) redS[ct][lane] = r;
    __syncthreads();
    if (!kh) {
        f32x4 o = redS[ct][lane];
        float4 st;
        st.x = r[0] + o[0]; st.y = r[1] + o[1];
        st.z = r[2] + o[2]; st.w = r[3] + o[3];
        *(float4*)&zA[(long)(r0 + l15) * U + cb + lq * 4] = st;
    }
}

// ---------------------------------------------------------------------------
// k_picard v4b: REGISTER-ONLY recurrence (R17 structure, passing) with the
// VCC-serialized f32 division in tanh replaced by pipelined v_rcp_f32.
// Tile->column map M(t,m) = 32*(t>>1) + 8*(m>>2) + 4*(t&1) + (m&3) makes the
// swapped-MFMA D output lane-locally identical to the next B-operand:
//   B-frag[ks] = { zr[2ks][0..3], zr[2ks+1][0..3] }.
// No LDS, no barriers, no shuffles in the whole kernel until phase 3's
// softmax reduction.
// grid = B/16 blocks x 64 threads (one wave, 16 rows x 128 cols).
// ---------------------------------------------------------------------------
__global__ __launch_bounds__(64, 1) void k_picard(
        const float* __restrict__ zA, const float* __restrict__ Wb,
        const float* __restrict__ Wo, const float* __restrict__ bo,
        float* __restrict__ Out, int L) {
    const int lane = threadIdx.x & 63;
    const int l15  = lane & 15;
    const int lq   = lane >> 4;
    const int r0   = blockIdx.x * 16;

    int rowM[8], colB[8];
    #pragma unroll
    for (int t = 0; t < 8; ++t) {
        rowM[t] = 32 * (t >> 1) + 8 * (l15 >> 2) + 4 * (t & 1) + (l15 & 3);
        colB[t] = 32 * (t >> 1) + 8 * lq + 4 * (t & 1);
    }

    // x for layer 0 (D-layout under M): xf[t][i] = zlin[r0+l15][colB[t]+i]
    f32x4 xf[8];
    #pragma unroll
    for (int t = 0; t < 8; ++t) {
        float4 v = *(const float4*)&zA[(long)(r0 + l15) * U + colB[t]];
        xf[t][0] = v.x; xf[t][1] = v.y; xf[t][2] = v.z; xf[t][3] = v.w;
    }

    u32x2 zpk[8];   // current z, RTNE-bf16 packed pairs (the B-operand data)

    // build the 4 B-frags from zpk (pure register moves)
    #define BUILD_B(B)                                                     \
    {   _Pragma("unroll")                                                  \
        for (int ks = 0; ks < 4; ++ks) {                                   \
            u32x4 b_;                                                      \
            b_[0] = zpk[2 * ks][0];     b_[1] = zpk[2 * ks][1];            \
            b_[2] = zpk[2 * ks + 1][0]; b_[3] = zpk[2 * ks + 1][1];        \
            B[ks] = __builtin_bit_cast(bf16x8, b_);                        \
        } }

    for (int l = 0; l < L; ++l) {
        const float* wl0 = &Wb[(long)l * U * U];

        // Wh (RTNE 1-term) -> registers for the whole layer (A-frag rows M)
        bf16x8 whf[8][4];
        #pragma unroll
        for (int t = 0; t < 8; ++t) {
            const float* wrow = &wl0[rowM[t] * U];
            #pragma unroll
            for (int ks = 0; ks < 4; ++ks) {
                const float* wp = &wrow[32 * ks + 8 * lq];
                float4 p = *(const float4*)&wp[0];
                float4 q = *(const float4*)&wp[4];
                u32x4 h;
                h[0] = packrn(p.x, p.y); h[1] = packrn(p.z, p.w);
                h[2] = packrn(q.x, q.y); h[3] = packrn(q.z, q.w);
                whf[t][ks] = __builtin_bit_cast(bf16x8, h);
            }
        }

        // z0 = tanh(x)
        #pragma unroll
        for (int t = 0; t < 8; ++t) {
            float z0 = tanh_fast(xf[t][0]), z1 = tanh_fast(xf[t][1]);
            float z2 = tanh_fast(xf[t][2]), z3 = tanh_fast(xf[t][3]);
            zpk[t][0] = packrn(z0, z1);
            zpk[t][1] = packrn(z2, z3);
        }

        // NIT register-only iterations (1-term W)
        for (int it = 0; it < NIT; ++it) {
            bf16x8 B[4];
            BUILD_B(B)                 // copies: safe to overwrite zpk below
            #pragma unroll
            for (int t = 0; t < 8; ++t) {
                f32x4 d = xf[t];
                d = MFMA(whf[t][0], B[0], d);
                d = MFMA(whf[t][1], B[1], d);
                d = MFMA(whf[t][2], B[2], d);
                d = MFMA(whf[t][3], B[3], d);
                float z0 = tanh_fast(d[0]), z1 = tanh_fast(d[1]);
                float z2 = tanh_fast(d[2]), z3 = tanh_fast(d[3]);
                zpk[t][0] = packrn(z0, z1);
                zpk[t][1] = packrn(z2, z3);
            }
        }

        // One exact-W correction iteration (JIT W-lo). Result -> xf (f32).
        {
            bf16x8 B[4];
            BUILD_B(B)
            #pragma unroll
            for (int t = 0; t < 8; ++t) {
                const float* wrow = &wl0[rowM[t] * U];
                f32x4 d = xf[t];
                #pragma unroll
                for (int ks = 0; ks < 4; ++ks) {
                    const float* wp = &wrow[32 * ks + 8 * lq];
                    float4 p = *(const float4*)&wp[0];
                    float4 q = *(const float4*)&wp[4];
                    u32x4 h = __builtin_bit_cast(u32x4, whf[t][ks]);
                    float lo0 = p.x - __uint_as_float(h[0] << 16);
                    float lo1 = p.y - __uint_as_float(h[0] & 0xFFFF0000u);
                    float lo2 = p.z - __uint_as_float(h[1] << 16);
                    float lo3 = p.w - __uint_as_float(h[1] & 0xFFFF0000u);
                    float lo4 = q.x - __uint_as_float(h[2] << 16);
                    float lo5 = q.y - __uint_as_float(h[2] & 0xFFFF0000u);
                    float lo6 = q.z - __uint_as_float(h[3] << 16);
                    float lo7 = q.w - __uint_as_float(h[3] & 0xFFFF0000u);
                    u32x4 lw;
                    lw[0] = packrn(lo0, lo1); lw[1] = packrn(lo2, lo3);
                    lw[2] = packrn(lo4, lo5); lw[3] = packrn(lo6, lo7);
                    bf16x8 wlf = __builtin_bit_cast(bf16x8, lw);
                    d = MFMA(whf[t][ks], B[ks], d);
                    d = MFMA(wlf, B[ks], d);
                }
                xf[t][0] = tanh_fast(d[0]);
                xf[t][1] = tanh_fast(d[1]);
                xf[t][2] = tanh_fast(d[2]);
                xf[t][3] = tanh_fast(d[3]);
            }
        }
    }

    // ---------------- Phase 3: out = softmax(z @ Wo^T + bo) ----------------
    // 3-term z (hi + lo), all in-register via the same lane-local B build.
    u32x2 zlo[8];
    #pragma unroll
    for (int t = 0; t < 8; ++t) {
        unsigned int h0 = packrn(xf[t][0], xf[t][1]);
        unsigned int h1 = packrn(xf[t][2], xf[t][3]);
        zpk[t][0] = h0; zpk[t][1] = h1;
        float lo0 = xf[t][0] - __uint_as_float(h0 << 16);
        float lo1 = xf[t][1] - __uint_as_float(h0 & 0xFFFF0000u);
        float lo2 = xf[t][2] - __uint_as_float(h1 << 16);
        float lo3 = xf[t][3] - __uint_as_float(h1 & 0xFFFF0000u);
        zlo[t][0] = packrn(lo0, lo1);
        zlo[t][1] = packrn(lo2, lo3);
    }
    bf16x8 Bh[4], Bl[4];
    BUILD_B(Bh)
    {   // build Bl from zlo
        #pragma unroll
        for (int ks = 0; ks < 4; ++ks) {
            u32x4 b_;
            b_[0] = zlo[2 * ks][0];     b_[1] = zlo[2 * ks][1];
            b_[2] = zlo[2 * ks + 1][0]; b_[3] = zlo[2 * ks + 1][1];
            Bl[ks] = __builtin_bit_cast(bf16x8, b_);
        }
    }

    // A-frag: Wo rows (classes, pad >=10 with zeros), 2-term split.
    // Wo k-cols are physical (k-slot -> col map is identity).
    bf16x8 woh[4], wol[4];
    #pragma unroll
    for (int ks = 0; ks < 4; ++ks) {
        float4 p = make_float4(0.f, 0.f, 0.f, 0.f), q = p;
        if (l15 < 10) {
            const float* worow = &Wo[l15 * U + ks * 32 + lq * 8];
            p = *(const float4*)&worow[0];
            q = *(const float4*)&worow[4];
        }
        SPLIT8(p, q, woh[ks], wol[ks])
    }

    f32x4 d0 = {0.f, 0.f, 0.f, 0.f};
    f32x4 d1 = d0, d2 = d0;
    #pragma unroll
    for (int ks = 0; ks < 4; ++ks) {
        d0 = MFMA(woh[ks], Bh[ks], d0);
        d1 = MFMA(wol[ks], Bh[ks], d1);
        d2 = MFMA(woh[ks], Bl[ks], d2);
    }
    // lane l15 = batch row, reg i -> class 4lq+i
    float lg[4];
    #pragma unroll
    for (int i = 0; i < 4; ++i) {
        const int c = 4 * lq + i;
        lg[i] = (c < 10) ? (d0[i] + d1[i] + d2[i] + bo[c]) : -1e30f;
    }
    float m = fmaxf(fmaxf(lg[0], lg[1]), fmaxf(lg[2], lg[3]));
    m = fmaxf(m, __shfl_xor(m, 16));
    m = fmaxf(m, __shfl_xor(m, 32));
    float e[4], s = 0.f;
    #pragma unroll
    for (int i = 0; i < 4; ++i) { e[i] = __expf(lg[i] - m); s += e[i]; }
    s += __shfl_xor(s, 16);
    s += __shfl_xor(s, 32);
    const float inv = rcp_fast(s);
    float sc = s * inv;                 // ~1 correction step for 1/s accuracy
    const float inv2 = inv * (2.0f - sc);
    #pragma unroll
    for (int i = 0; i < 4; ++i) {
        const int c = 4 * lq + i;
        if (c < 10) Out[(long)(r0 + l15) * 10 + c] = e[i] * inv2;
    }
}

// ---------------------------------------------------------------------------
extern "C" void kernel_launch(void* const* d_in, const int* in_sizes, int n_in,
                              void* d_out, int out_size, void* d_ws, size_t ws_size,
                              hipStream_t stream) {
    const float* x  = (const float*)d_in[0];   // [B,784]
    const float* Wi = (const float*)d_in[1];   // [128,784]
    const float* bi = (const float*)d_in[2];   // [128]
    const float* Wb = (const float*)d_in[3];   // [L,128,128]
    const float* Wo = (const float*)d_in[4];   // [10,128]
    const float* bo = (const float*)d_in[5];   // [10]
    float* out = (float*)d_out;

    const int DIN = 784;
    const int B   = in_sizes[0] / DIN;             // 2048
    const int L   = in_sizes[3] / (U * U);         // 2

    float* zA = (float*)d_ws;                      // [B,U] f32

    k_gemm_in<<<256, 512, 0, stream>>>(x, Wi, bi, zA);
    k_picard<<<B / 16, 64, 0, stream>>>(zA, Wb, Wo, bo, out, L);
}

// Round 19
// 29.291 us; speedup vs baseline: 2.6895x; 1.6293x over previous
//
#include <hip/hip_runtime.h>
#include <math.h>

#define U 128
#define NIT 10   // fixed Picard iters/layer (even); validated R10/R12 numerics

typedef __attribute__((ext_vector_type(8))) short bf16x8;
typedef __attribute__((ext_vector_type(4))) float f32x4;
typedef __attribute__((ext_vector_type(4))) unsigned int u32x4;

__device__ inline unsigned int pack2(float a, float b) {
    // low short = bf16(a) (truncated), high short = bf16(b)
    return (__float_as_uint(a) >> 16) | (__float_as_uint(b) & 0xFFFF0000u);
}
__device__ inline float lo_of(float a) {
    return a - __uint_as_float(__float_as_uint(a) & 0xFFFF0000u);
}
__device__ inline unsigned int packrn(float a, float b) {
    // RTNE pack (v_cvt_pk_bf16_f32): low = bf16_rn(a), high = bf16_rn(b)
    unsigned int r;
    asm("v_cvt_pk_bf16_f32 %0, %1, %2" : "=v"(r) : "v"(a), "v"(b));
    return r;
}
__device__ inline float fromhi(unsigned short h) {
    return __uint_as_float(((unsigned int)h) << 16);
}
// R17/R18 lesson: f32 division expands to v_div_scale/v_div_fmas/v_div_fixup
// which serialize through VCC (~150cy each, no pipelining). v_rcp_f32 is a
// plain pipelined transcendental (~1 ULP) -- validated in R18: absmax
// bit-identical (0.001953125).
__device__ inline float rcp_fast(float x) {
    float r;
    asm("v_rcp_f32 %0, %1" : "=v"(r) : "v"(x));
    return r;
}
__device__ inline float tanh_fast(float v) {
    float e = __expf(2.0f * v);
    return __builtin_fmaf(-2.0f, rcp_fast(e + 1.0f), 1.0f);
}
#define MFMA(A, B, C) __builtin_amdgcn_mfma_f32_16x16x32_bf16(A, B, C, 0, 0, 0)

// in-register f32 -> (trunc-bf16 hi, bf16 lo) split of 8 values
#define SPLIT8(P4, Q4, H, LO)                                              \
{   u32x4 h_, l_;                                                          \
    h_[0] = pack2(P4.x, P4.y); h_[1] = pack2(P4.z, P4.w);                  \
    h_[2] = pack2(Q4.x, Q4.y); h_[3] = pack2(Q4.z, Q4.w);                  \
    l_[0] = pack2(lo_of(P4.x), lo_of(P4.y));                               \
    l_[1] = pack2(lo_of(P4.z), lo_of(P4.w));                               \
    l_[2] = pack2(lo_of(Q4.x), lo_of(Q4.y));                               \
    l_[3] = pack2(lo_of(Q4.z), lo_of(Q4.w));                               \
    H  = __builtin_bit_cast(bf16x8, h_);                                   \
    LO = __builtin_bit_cast(bf16x8, l_); }

// ---------------------------------------------------------------------------
// k_gemm_in: zA = X @ Wi^T + bi (f32). R10 version (measured 8.8us, R11).
// ---------------------------------------------------------------------------
__global__ __launch_bounds__(512) void k_gemm_in(
        const float* __restrict__ X, const float* __restrict__ Wi,
        const float* __restrict__ bi, float* __restrict__ zA) {
    __shared__ f32x4 redS[4][64];
    const int tid  = threadIdx.x;
    const int w    = tid >> 6;
    const int lane = tid & 63;
    const int l15  = lane & 15;
    const int lq   = lane >> 4;
    const int slab = blockIdx.x & 127;
    const int ch   = blockIdx.x >> 7;
    const int ct   = w & 3;
    const int kh   = w >> 2;
    const int r0   = slab * 16;
    const int cb   = ch * 64 + ct * 16;
    const int colA = cb + l15;
    const int KD   = 784;

    const float* xp = &X[(long)(r0 + l15) * KD];
    const float* wp = &Wi[(long)colA * KD];

    f32x4 a0 = {0.f, 0.f, 0.f, 0.f};
    f32x4 a1 = {0.f, 0.f, 0.f, 0.f};
    f32x4 a2 = {0.f, 0.f, 0.f, 0.f};
    if (kh == 0) {
        float4 b4 = *(const float4*)&bi[cb + lq * 4];
        a0[0] = b4.x; a0[1] = b4.y; a0[2] = b4.z; a0[3] = b4.w;
    }

    const int kbase = kh ? 384 : 0;
    #pragma unroll 6
    for (int c = 0; c < 12; ++c) {
        const int k = kbase + c * 32 + lq * 8;
        float4 xa = *(const float4*)&xp[k];
        float4 xb = *(const float4*)&xp[k + 4];
        float4 wa = *(const float4*)&wp[k];
        float4 wb = *(const float4*)&wp[k + 4];
        bf16x8 ah, al, bh, bl;
        SPLIT8(xa, xb, ah, al)
        SPLIT8(wa, wb, bh, bl)
        a0 = MFMA(bh, ah, a0);     // Wh . xh
        a1 = MFMA(bh, al, a1);     // Wh . xl
        a2 = MFMA(bl, ah, a2);     // Wl . xh
    }
    if (kh) {   // tail k = 768..783 (valid lq<2)
        float4 z4 = make_float4(0.f, 0.f, 0.f, 0.f);
        float4 xa = z4, xb = z4, wa = z4, wb = z4;
        if (lq < 2) {
            const int k = 768 + lq * 8;
            xa = *(const float4*)&xp[k];
            xb = *(const float4*)&xp[k + 4];
            wa = *(const float4*)&wp[k];
            wb = *(const float4*)&wp[k + 4];
        }
        bf16x8 ah, al, bh, bl;
        SPLIT8(xa, xb, ah, al)
        SPLIT8(wa, wb, bh, bl)
        a0 = MFMA(bh, ah, a0);
        a1 = MFMA(bh, al, a1);
        a2 = MFMA(bl, ah, a2);
    }

    f32x4 r;
    #pragma unroll
    for (int i = 0; i < 4; ++i) r[i] = a0[i] + a1[i] + a2[i];

    if (kh) redS[ct][lane] = r;
    __syncthreads();
    if (!kh) {
        f32x4 o = redS[ct][lane];
        float4 st;
        st.x = r[0] + o[0]; st.y = r[1] + o[1];
        st.z = r[2] + o[2]; st.w = r[3] + o[3];
        *(float4*)&zA[(long)(r0 + l15) * U + cb + lq * 4] = st;
    }
}

// ---------------------------------------------------------------------------
// k_picard: R12's PASSING structure (4 waves x 2 col-tiles, bf16-hi LDS
// ping-pong, barrier per iter) with the VCC-division removed from tanh.
// grid: B/16 blocks, 256 threads. Wave w owns cols 32w..32w+31.
// Final z written hi+lo for the 3-term output GEMM (removes final quant
// floor); phase 3 on wave 0 via MFMA + 2-level shuffle softmax.
// LDS z: byte(r,c) = r*256 + ((2c) ^ ((r&7)<<4))  XOR swizzle.
// ---------------------------------------------------------------------------
__global__ __launch_bounds__(256) void k_picard(
        const float* __restrict__ zA, const float* __restrict__ Wb,
        const float* __restrict__ Wo, const float* __restrict__ bo,
        float* __restrict__ Out, int L) {
    __shared__ unsigned short zhS[2][16 * U];   // 2 x 4 KB (dbuf; buf1 = z_lo at end)

    const int tid  = threadIdx.x;
    const int w    = tid >> 6;          // 0..3
    const int lane = tid & 63;
    const int l15  = lane & 15;
    const int lq   = lane >> 4;
    const int r0   = blockIdx.x * 16;

    // x (z-lin): lane l15 = batch row; regs: ct0 cols 32w+4lq..+3, ct1 +16
    float xf[8], zr[8];
    {
        const float* zrow = &zA[(long)(r0 + l15) * U + w * 32 + lq * 4];
        float4 x40 = *(const float4*)&zrow[0];
        float4 x41 = *(const float4*)&zrow[16];
        xf[0] = x40.x; xf[1] = x40.y; xf[2] = x40.z; xf[3] = x40.w;
        xf[4] = x41.x; xf[5] = x41.y; xf[6] = x41.z; xf[7] = x41.w;
    }

    const int swz = (l15 & 7) << 4;
    int offA[4];
    #pragma unroll
    for (int ks = 0; ks < 4; ++ks)
        offA[ks] = l15 * 256 + ((64 * ks + 16 * lq) ^ swz);
    const int offW0 = l15 * 256 + (((64 * w + 8 * lq)) ^ swz);        // ct0
    const int offW1 = l15 * 256 + (((64 * w + 32 + 8 * lq)) ^ swz);   // ct1

    char* zhB = (char*)&zhS[0][0];

    for (int l = 0; l < L; ++l) {
        // layer weights for both col-tiles: f32 -> 3-term split in registers
        bf16x8 whf[2][4], wlf[2][4];
        #pragma unroll
        for (int ct = 0; ct < 2; ++ct) {
            const int colA = w * 32 + ct * 16 + l15;
            const float* wrow = &Wb[((long)l * U + colA) * U];
            #pragma unroll
            for (int ks = 0; ks < 4; ++ks) {
                const int k = ks * 32 + lq * 8;
                float4 p = *(const float4*)&wrow[k];
                float4 q = *(const float4*)&wrow[k + 4];
                SPLIT8(p, q, whf[ct][ks], wlf[ct][ks])
            }
        }

        // z0 = tanh(x) -> buffer 0
        {
            uint2 h0, h1;
            #pragma unroll
            for (int i = 0; i < 8; ++i) zr[i] = tanh_fast(xf[i]);
            h0.x = packrn(zr[0], zr[1]); h0.y = packrn(zr[2], zr[3]);
            h1.x = packrn(zr[4], zr[5]); h1.y = packrn(zr[6], zr[7]);
            *(uint2*)(zhB + offW0) = h0;
            *(uint2*)(zhB + offW1) = h1;
        }
        __syncthreads();

        #pragma unroll 2
        for (int it = 0; it < NIT; ++it) {
            const int cur = it & 1;
            const int nxt = cur ^ 1;
            bf16x8 zhf[4];
            #pragma unroll
            for (int ks = 0; ks < 4; ++ks)
                zhf[ks] = *(const bf16x8*)(zhB + cur * 4096 + offA[ks]);

            // 8 independent chains (2 ct x {hi,lo} x 2 halves), depth 2
            f32x4 A0 = {xf[0], xf[1], xf[2], xf[3]};
            f32x4 Z4 = {0.f, 0.f, 0.f, 0.f};
            f32x4 A1 = Z4, A2 = Z4, A3 = Z4;
            f32x4 B0 = {xf[4], xf[5], xf[6], xf[7]};
            f32x4 B1 = Z4, B2 = Z4, B3 = Z4;
            A0 = MFMA(whf[0][0], zhf[0], A0);
            B0 = MFMA(whf[1][0], zhf[0], B0);
            A1 = MFMA(whf[0][2], zhf[2], A1);
            B1 = MFMA(whf[1][2], zhf[2], B1);
            A2 = MFMA(wlf[0][0], zhf[0], A2);
            B2 = MFMA(wlf[1][0], zhf[0], B2);
            A3 = MFMA(wlf[0][2], zhf[2], A3);
            B3 = MFMA(wlf[1][2], zhf[2], B3);
            A0 = MFMA(whf[0][1], zhf[1], A0);
            B0 = MFMA(whf[1][1], zhf[1], B0);
            A1 = MFMA(whf[0][3], zhf[3], A1);
            B1 = MFMA(whf[1][3], zhf[3], B1);
            A2 = MFMA(wlf[0][1], zhf[1], A2);
            B2 = MFMA(wlf[1][1], zhf[1], B2);
            A3 = MFMA(wlf[0][3], zhf[3], A3);
            B3 = MFMA(wlf[1][3], zhf[3], B3);

            #pragma unroll
            for (int i = 0; i < 4; ++i) {
                zr[i]     = tanh_fast(A0[i] + A1[i] + A2[i] + A3[i]);
                zr[4 + i] = tanh_fast(B0[i] + B1[i] + B2[i] + B3[i]);
            }
            uint2 h0, h1;
            h0.x = packrn(zr[0], zr[1]); h0.y = packrn(zr[2], zr[3]);
            h1.x = packrn(zr[4], zr[5]); h1.y = packrn(zr[6], zr[7]);
            *(uint2*)(zhB + nxt * 4096 + offW0) = h0;
            *(uint2*)(zhB + nxt * 4096 + offW1) = h1;
            __syncthreads();
        }
        #pragma unroll
        for (int i = 0; i < 8; ++i) xf[i] = zr[i];   // next layer input
    }
    // NIT even => final z hi in buffer 0. Write z_lo (residual vs stored hi)
    // to buffer 1 for the 3-term output GEMM.
    {
        uint2 l0, l1;
        l0.x = packrn(zr[0] - fromhi((unsigned short)(packrn(zr[0], zr[0]))),
                      zr[1] - fromhi((unsigned short)(packrn(zr[1], zr[1]))));
        l0.y = packrn(zr[2] - fromhi((unsigned short)(packrn(zr[2], zr[2]))),
                      zr[3] - fromhi((unsigned short)(packrn(zr[3], zr[3]))));
        l1.x = packrn(zr[4] - fromhi((unsigned short)(packrn(zr[4], zr[4]))),
                      zr[5] - fromhi((unsigned short)(packrn(zr[5], zr[5]))));
        l1.y = packrn(zr[6] - fromhi((unsigned short)(packrn(zr[6], zr[6]))),
                      zr[7] - fromhi((unsigned short)(packrn(zr[7], zr[7]))));
        *(uint2*)(zhB + 4096 + offW0) = l0;
        *(uint2*)(zhB + 4096 + offW1) = l1;
    }
    __syncthreads();

    // ---------------- Phase 3 (wave 0): out = softmax(z @ Wo^T + bo) -------
    if (w == 0) {
        // A-frag: Wo rows (classes, pad >=10 with zeros), 2-term split
        bf16x8 woh[4], wol[4];
        #pragma unroll
        for (int ks = 0; ks < 4; ++ks) {
            float4 p = make_float4(0.f, 0.f, 0.f, 0.f), q = p;
            if (l15 < 10) {
                const float* worow = &Wo[l15 * U + ks * 32 + lq * 8];
                p = *(const float4*)&worow[0];
                q = *(const float4*)&worow[4];
            }
            SPLIT8(p, q, woh[ks], wol[ks])
        }
        // B-frags: final z hi (buf0) + lo (buf1)
        bf16x8 zf[4], zl[4];
        #pragma unroll
        for (int ks = 0; ks < 4; ++ks) {
            zf[ks] = *(const bf16x8*)(zhB + offA[ks]);
            zl[ks] = *(const bf16x8*)(zhB + 4096 + offA[ks]);
        }

        f32x4 d0 = {0.f, 0.f, 0.f, 0.f};
        f32x4 d1 = d0, d2 = d0;
        #pragma unroll
        for (int ks = 0; ks < 4; ++ks) {
            d0 = MFMA(woh[ks], zf[ks], d0);
            d1 = MFMA(wol[ks], zf[ks], d1);
            d2 = MFMA(woh[ks], zl[ks], d2);
        }
        // lane l15 = batch row, reg i -> class 4lq+i
        float lg[4];
        #pragma unroll
        for (int i = 0; i < 4; ++i) {
            const int c = 4 * lq + i;
            lg[i] = (c < 10) ? (d0[i] + d1[i] + d2[i] + bo[c]) : -1e30f;
        }
        float m = fmaxf(fmaxf(lg[0], lg[1]), fmaxf(lg[2], lg[3]));
        m = fmaxf(m, __shfl_xor(m, 16));
        m = fmaxf(m, __shfl_xor(m, 32));
        float e[4], s = 0.f;
        #pragma unroll
        for (int i = 0; i < 4; ++i) { e[i] = __expf(lg[i] - m); s += e[i]; }
        s += __shfl_xor(s, 16);
        s += __shfl_xor(s, 32);
        const float inv = rcp_fast(s);
        const float inv2 = inv * (2.0f - s * inv);   // one NR step
        #pragma unroll
        for (int i = 0; i < 4; ++i) {
            const int c = 4 * lq + i;
            if (c < 10) Out[(long)(r0 + l15) * 10 + c] = e[i] * inv2;
        }
    }
}

// ---------------------------------------------------------------------------
extern "C" void kernel_launch(void* const* d_in, const int* in_sizes, int n_in,
                              void* d_out, int out_size, void* d_ws, size_t ws_size,
                              hipStream_t stream) {
    const float* x  = (const float*)d_in[0];   // [B,784]
    const float* Wi = (const float*)d_in[1];   // [128,784]
    const float* bi = (const float*)d_in[2];   // [128]
    const float* Wb = (const float*)d_in[3];   // [L,128,128]
    const float* Wo = (const float*)d_in[4];   // [10,128]
    const float* bo = (const float*)d_in[5];   // [10]
    float* out = (float*)d_out;

    const int DIN = 784;
    const int B   = in_sizes[0] / DIN;             // 2048
    const int L   = in_sizes[3] / (U * U);         // 2

    float* zA = (float*)d_ws;                      // [B,U] f32

    k_gemm_in<<<256, 512, 0, stream>>>(x, Wi, bi, zA);
    k_picard<<<B / 16, 256, 0, stream>>>(zA, Wb, Wo, bo, out, L);
}